// Round 1
// baseline (1650.359 us; speedup 1.0000x reference)
//
#include <hip/hip_runtime.h>
#include <hip/hip_bf16.h>

#define BB 256      // batch
#define TT 2048     // timesteps
#define DD 32       // obs dim
#define HH 64       // hidden
#define GG 256      // 4*H gates
#define CHUNK 64    // timesteps of x staged per LDS refill

__device__ __forceinline__ float fast_sigmoid(float x) {
    return 1.0f / (1.0f + __expf(-x));
}
__device__ __forceinline__ float fast_tanh(float x) {
    // 1 - 2/(1+exp(2x)); saturates correctly for large |x|
    return 1.0f - 2.0f / (1.0f + __expf(2.0f * x));
}

__global__ __launch_bounds__(256, 1) void lstm_seq_kernel(
    const float* __restrict__ y,    // [B, T, D]
    const float* __restrict__ Wx,   // [D, 4H]
    const float* __restrict__ Wh,   // [H, 4H]
    const float* __restrict__ b,    // [4H]
    float* __restrict__ out)        // [B, T, H]
{
    const int j = threadIdx.x;        // gate column 0..255
    const int batch = blockIdx.x;     // 0..255

    __shared__ float xs[CHUNK * DD];  // 8 KiB staged inputs
    __shared__ float hs[HH];          // hidden state
    __shared__ float gates[GG];       // pre-activation gates

    // ---- load weight columns into registers (coalesced: fixed k, consecutive j)
    float wx[DD];
#pragma unroll
    for (int k = 0; k < DD; ++k) wx[k] = Wx[k * GG + j];
    float wh[HH];
#pragma unroll
    for (int k = 0; k < HH; ++k) wh[k] = Wh[k * GG + j];
    const float bj = b[j];

    float c = 0.0f;                   // cell state lives in lanes 0..63
    if (j < HH) hs[j] = 0.0f;
    __syncthreads();

    const float* ybase = y + (size_t)batch * TT * DD;
    float* obase = out + (size_t)batch * TT * HH;

    for (int t0 = 0; t0 < TT; t0 += CHUNK) {
        // ---- stage CHUNK*DD = 2048 floats = 512 float4; 2 per thread
        {
            const float4* src = (const float4*)(ybase + (size_t)t0 * DD);
            float4* dst = (float4*)xs;
            dst[j] = src[j];
            dst[j + 256] = src[j + 256];
        }
        __syncthreads();

        for (int tl = 0; tl < CHUNK; ++tl) {
            // ---- gates[j] = b[j] + x.Wx[:,j] + h.Wh[:,j], 4-way ILP accumulators
            float acc0 = bj, acc1 = 0.0f, acc2 = 0.0f, acc3 = 0.0f;
            const float4* xp = (const float4*)(xs + tl * DD);
#pragma unroll
            for (int k = 0; k < DD / 4; ++k) {
                float4 xv = xp[k];
                acc0 = fmaf(xv.x, wx[4 * k + 0], acc0);
                acc1 = fmaf(xv.y, wx[4 * k + 1], acc1);
                acc2 = fmaf(xv.z, wx[4 * k + 2], acc2);
                acc3 = fmaf(xv.w, wx[4 * k + 3], acc3);
            }
            const float4* hp = (const float4*)hs;
#pragma unroll
            for (int k = 0; k < HH / 4; ++k) {
                float4 hv = hp[k];
                acc0 = fmaf(hv.x, wh[4 * k + 0], acc0);
                acc1 = fmaf(hv.y, wh[4 * k + 1], acc1);
                acc2 = fmaf(hv.z, wh[4 * k + 2], acc2);
                acc3 = fmaf(hv.w, wh[4 * k + 3], acc3);
            }
            gates[j] = (acc0 + acc1) + (acc2 + acc3);
            __syncthreads();

            // ---- lanes 0..63: elementwise LSTM cell update
            if (j < HH) {
                float ig = fast_sigmoid(gates[j]);
                float fg = fast_sigmoid(gates[HH + j]);
                float gg = fast_tanh(gates[2 * HH + j]);
                float og = fast_sigmoid(gates[3 * HH + j]);
                c = fg * c + ig * gg;
                float h = og * fast_tanh(c);
                hs[j] = h;
                obase[(size_t)(t0 + tl) * HH + j] = h;
            }
            __syncthreads();
        }
    }
}

extern "C" void kernel_launch(void* const* d_in, const int* in_sizes, int n_in,
                              void* d_out, int out_size, void* d_ws, size_t ws_size,
                              hipStream_t stream) {
    const float* y  = (const float*)d_in[0];
    const float* Wx = (const float*)d_in[1];
    const float* Wh = (const float*)d_in[2];
    const float* b  = (const float*)d_in[3];
    float* out = (float*)d_out;

    lstm_seq_kernel<<<BB, GG, 0, stream>>>(y, Wx, Wh, b, out);
}

// Round 2
// 1604.446 us; speedup vs baseline: 1.0286x; 1.0286x over previous
//
#include <hip/hip_runtime.h>
#include <hip/hip_bf16.h>

#define BB 256      // batch
#define TT 2048     // timesteps
#define DD 32       // obs dim
#define HH 64       // hidden
#define GG 256      // 4*H gates

__device__ __forceinline__ float fast_sig(float x) {
    // v_rcp + v_exp, ~1 ulp each; plenty for 1.17e-2 threshold
    return __builtin_amdgcn_rcpf(1.0f + __expf(-x));
}

__global__ __launch_bounds__(256, 1) void lstm_seq_kernel(
    const float* __restrict__ y,    // [B, T, D]
    const float* __restrict__ Wx,   // [D, 4H]
    const float* __restrict__ Wh,   // [H, 4H]
    const float* __restrict__ b,    // [4H]
    float* __restrict__ out)        // [B, T, H]
{
    const int j = threadIdx.x;        // gate column 0..255
    const int w = j >> 6;             // wave id: 0=i, 1=f, 2=g, 3=o
    const int l = j & 63;             // hidden unit owned by this lane
    const int batch = blockIdx.x;

    __shared__ float hbuf[4][HH];     // per-wave private h copy (no cross-wave hazard)
    __shared__ float gbuf[2][GG];     // double-buffered activated gates

    // weight columns in registers (coalesced loads: fixed k, consecutive j)
    float wx[DD];
#pragma unroll
    for (int k = 0; k < DD; ++k) wx[k] = Wx[k * GG + j];
    float wh[HH];
#pragma unroll
    for (int k = 0; k < HH; ++k) wh[k] = Wh[k * GG + j];
    const float bj = b[j];

    // wave-uniform activation selector: sigmoid for i,f,o; tanh = 2*sig(2x)-1 for g
    const bool isg = (w == 2);
    const float sc = isg ? 2.0f : 1.0f;
    const float aa = isg ? 2.0f : 1.0f;
    const float ab = isg ? -1.0f : 0.0f;

    float c = 0.0f;                   // replicated cell state for unit l (all waves)
    hbuf[w][l] = 0.0f;                // own-wave h copy init

    const float* ybase = y + (size_t)batch * (TT * DD);
    float* obase = out + (size_t)batch * (TT * HH);

    // prefetch x row 0 into registers (broadcast: all lanes same addr -> 1 req)
    float4 xr[DD / 4];
    {
        const float4* row = (const float4*)ybase;
#pragma unroll
        for (int q = 0; q < DD / 4; ++q) xr[q] = row[q];
    }
    __syncthreads();

    int buf = 0;
    for (int t = 0; t < TT; ++t) {
        // ---- x contribution from registers, 4-way ILP accumulators
        float a0 = bj, a1 = 0.0f, a2 = 0.0f, a3 = 0.0f;
#pragma unroll
        for (int q = 0; q < DD / 4; ++q) {
            float4 xv = xr[q];
            a0 = fmaf(xv.x, wx[4 * q + 0], a0);
            a1 = fmaf(xv.y, wx[4 * q + 1], a1);
            a2 = fmaf(xv.z, wx[4 * q + 2], a2);
            a3 = fmaf(xv.w, wx[4 * q + 3], a3);
        }
        // ---- prefetch next x row (hidden a full step ahead; clamp at T-1)
        {
            const int tn = (t + 1 < TT) ? (t + 1) : t;
            const float4* row = (const float4*)(ybase + (size_t)tn * DD);
#pragma unroll
            for (int q = 0; q < DD / 4; ++q) xr[q] = row[q];
        }
        // ---- h contribution: broadcast reads from own wave's LDS copy
        const float4* hp = (const float4*)hbuf[w];
#pragma unroll
        for (int k = 0; k < HH / 4; ++k) {
            float4 hv = hp[k];
            a0 = fmaf(hv.x, wh[4 * k + 0], a0);
            a1 = fmaf(hv.y, wh[4 * k + 1], a1);
            a2 = fmaf(hv.z, wh[4 * k + 2], a2);
            a3 = fmaf(hv.w, wh[4 * k + 3], a3);
        }
        float g = (a0 + a1) + (a2 + a3);
        // ---- activation applied by the gate owner (parallel across 256 threads)
        gbuf[buf][j] = fmaf(aa, fast_sig(sc * g), ab);
        __syncthreads();   // the ONLY barrier per step

        // ---- every wave redundantly updates its replica of (c, h) for unit l
        float ig = gbuf[buf][l];
        float fg = gbuf[buf][HH + l];
        float gg = gbuf[buf][2 * HH + l];
        float og = gbuf[buf][3 * HH + l];
        c = fmaf(fg, c, ig * gg);
        float th = fmaf(2.0f, fast_sig(2.0f * c), -1.0f);   // tanh(c)
        float h = og * th;
        hbuf[w][l] = h;                 // own-wave copy; in-order LDS, no barrier
        if (w == 0) obase[(size_t)t * HH + l] = h;   // one wave writes output
        buf ^= 1;
    }
}

extern "C" void kernel_launch(void* const* d_in, const int* in_sizes, int n_in,
                              void* d_out, int out_size, void* d_ws, size_t ws_size,
                              hipStream_t stream) {
    const float* y  = (const float*)d_in[0];
    const float* Wx = (const float*)d_in[1];
    const float* Wh = (const float*)d_in[2];
    const float* b  = (const float*)d_in[3];
    float* out = (float*)d_out;

    lstm_seq_kernel<<<BB, GG, 0, stream>>>(y, Wx, Wh, b, out);
}

// Round 3
// 1514.362 us; speedup vs baseline: 1.0898x; 1.0595x over previous
//
#include <hip/hip_runtime.h>
#include <hip/hip_bf16.h>

#define BB 256      // batch
#define TT 2048     // timesteps
#define DD 32       // obs dim
#define HH 64       // hidden
#define GG 256      // 4*H gates
#define CHUNK 64    // timesteps of x per LDS refill
#define NCH (TT / CHUNK)

__device__ __forceinline__ float fast_sig(float x) {
    return __builtin_amdgcn_rcpf(1.0f + __expf(-x));
}

__global__ __launch_bounds__(256, 1) void lstm_seq_kernel(
    const float* __restrict__ y,    // [B, T, D]
    const float* __restrict__ Wx,   // [D, 4H]
    const float* __restrict__ Wh,   // [H, 4H]
    const float* __restrict__ b,    // [4H]
    float* __restrict__ out)        // [B, T, H]
{
    const int j = threadIdx.x;        // gate column 0..255
    const int w = j >> 6;             // wave id
    const int l = j & 63;             // lane / hidden unit
    const int batch = blockIdx.x;

    __shared__ float xbuf[4][CHUNK * DD];  // per-wave PRIVATE x chunk (8 KB each)
    __shared__ float hbuf[4][HH];          // per-wave PRIVATE h copy
    __shared__ float gbuf[2][GG];          // double-buffered activated gates

    // weight columns in registers (coalesced: fixed k, consecutive j)
    float wx[DD];
#pragma unroll
    for (int k = 0; k < DD; ++k) wx[k] = Wx[k * GG + j];
    float wh[HH];
#pragma unroll
    for (int k = 0; k < HH; ++k) wh[k] = Wh[k * GG + j];
    const float bj = b[j];

    // wave-uniform activation: sigmoid for i,f,o; tanh(x)=2*sig(2x)-1 for g (wave 2)
    const bool isg = (w == 2);
    const float sc = isg ? 2.0f : 1.0f;
    const float aa = isg ? 2.0f : 1.0f;
    const float ab = isg ? -1.0f : 0.0f;

    float c = 0.0f;                   // replicated cell state for unit l
    hbuf[w][l] = 0.0f;                // own-wave copy (in-wave ordering suffices)

    const float4* ysrc = (const float4*)(y + (size_t)batch * (TT * DD)); // 512 float4 per chunk
    float* obase = out + (size_t)batch * (TT * HH);

    // prefetch chunk 0 into registers: 2048 floats/wave, 8 float4 per lane
    float4 pf[8];
#pragma unroll
    for (int q = 0; q < 8; ++q) pf[q] = ysrc[q * 64 + l];

    __syncthreads();   // initial h/gbuf visibility

    int buf = 0;
    for (int ch = 0; ch < NCH; ++ch) {
        // ---- commit prefetched chunk to OWN wave's xbuf (no barrier needed:
        //      in-wave LDS ops complete in order; only this wave reads xbuf[w])
        float4* xw = (float4*)xbuf[w];
#pragma unroll
        for (int q = 0; q < 8; ++q) xw[q * 64 + l] = pf[q];
        // ---- prefetch NEXT chunk (consumed ~64 steps from now; latency free)
        {
            const int cn = (ch + 1 < NCH) ? (ch + 1) : ch;
#pragma unroll
            for (int q = 0; q < 8; ++q) pf[q] = ysrc[cn * 512 + q * 64 + l];
        }

        for (int tl = 0; tl < CHUNK; ++tl) {
            const int t = ch * CHUNK + tl;
            // ---- h reads issue first; latency hides under x-FMA block
            const float4* hp = (const float4*)hbuf[w];
            const float4* xp = (const float4*)(xbuf[w] + tl * DD);

            float a0 = bj, a1 = 0.0f, a2 = 0.0f, a3 = 0.0f;
#pragma unroll
            for (int q = 0; q < DD / 4; ++q) {
                float4 xv = xp[q];
                a0 = fmaf(xv.x, wx[4 * q + 0], a0);
                a1 = fmaf(xv.y, wx[4 * q + 1], a1);
                a2 = fmaf(xv.z, wx[4 * q + 2], a2);
                a3 = fmaf(xv.w, wx[4 * q + 3], a3);
            }
#pragma unroll
            for (int k = 0; k < HH / 4; ++k) {
                float4 hv = hp[k];
                a0 = fmaf(hv.x, wh[4 * k + 0], a0);
                a1 = fmaf(hv.y, wh[4 * k + 1], a1);
                a2 = fmaf(hv.z, wh[4 * k + 2], a2);
                a3 = fmaf(hv.w, wh[4 * k + 3], a3);
            }
            float g = (a0 + a1) + (a2 + a3);
            // activation by the gate owner (parallel across all 256 threads)
            gbuf[buf][j] = fmaf(aa, fast_sig(sc * g), ab);
            __syncthreads();   // the ONLY barrier per step

            // ---- every wave redundantly updates its replica of (c, h)
            float ig = gbuf[buf][l];
            float fg = gbuf[buf][HH + l];
            float gg = gbuf[buf][2 * HH + l];
            float og = gbuf[buf][3 * HH + l];
            c = fmaf(fg, c, ig * gg);
            float th = fmaf(2.0f, fast_sig(2.0f * c), -1.0f);   // tanh(c)
            float h = og * th;
            hbuf[w][l] = h;                         // own copy; in-wave ordering
            if (w == 0) obase[(size_t)t * HH + l] = h;
            buf ^= 1;
        }
    }
}

extern "C" void kernel_launch(void* const* d_in, const int* in_sizes, int n_in,
                              void* d_out, int out_size, void* d_ws, size_t ws_size,
                              hipStream_t stream) {
    const float* y  = (const float*)d_in[0];
    const float* Wx = (const float*)d_in[1];
    const float* Wh = (const float*)d_in[2];
    const float* b  = (const float*)d_in[3];
    float* out = (float*)d_out;

    lstm_seq_kernel<<<BB, GG, 0, stream>>>(y, Wx, Wh, b, out);
}